// Round 9
// baseline (130.132 us; speedup 1.0000x reference)
//
#include <hip/hip_runtime.h>

// net_86698209837440: N=100000, DEG=32 (edges sorted by tgt, deg==32), D=24, NK=2, H=64.
// R9: async gather. R7's wall = VGPR-starved gather issue (~8 serialized round trips
// per node, VGPR_Count=40); R8's register pipeline raced. Fix: __builtin_amdgcn_
// global_load_lds DMA gathers (no dest VGPR => compiler cannot re-serialize),
// double-buffered per-wave LDS tiles, explicit s_waitcnt vmcnt(8)/(0).
// Phase 1: [k0;k1;ones](3x32) @ gathered-x(32x24) via 2x mfma_f32_32x32x16_bf16.
// Phase 2: pre(32x48 bf16, LDS) @ W^T via MFMA. fp32 accumulation. NO sched_barrier.

#define NN   100000
#define DEG  32
#define EE   (NN * DEG)
#define DD   24
#define HH   64
#define NPB  32            // nodes per block; 100000 = 3125 * 32 exact
#define TPB  256
#define NPW  8             // nodes per wave
#define PST  56            // pre_s row stride (ushorts)

typedef __attribute__((ext_vector_type(8)))  short short8;
typedef __attribute__((ext_vector_type(16))) float float16;

__device__ __forceinline__ unsigned short f2bf(float f) {
    union { float f; unsigned u; } v; v.f = f;
    unsigned r = v.u + 0x7fffu + ((v.u >> 16) & 1u);   // RNE
    return (unsigned short)(r >> 16);
}

__device__ __forceinline__ float bf2f(unsigned u) {
    union { unsigned i; float f; } v; v.i = u << 16; return v.f;
}

// lo16(a) -> low half, lo16(b) -> high half, one v_perm_b32
__device__ __forceinline__ unsigned pk(unsigned a, unsigned b) {
    return __builtin_amdgcn_perm(b, a, 0x05040100u);
}

__device__ __forceinline__ short8 mk8(unsigned u0, unsigned u1, unsigned u2, unsigned u3) {
    union { unsigned u[4]; short8 s; } p;
    p.u[0] = u0; p.u[1] = u1; p.u[2] = u2; p.u[3] = u3;
    return p.s;
}

// async 4B gather: per-lane global addr -> (wave-uniform LDS base + lane*4)
__device__ __forceinline__ void gl_lds4(const void* g, void* l) {
    __builtin_amdgcn_global_load_lds(
        (const __attribute__((address_space(1))) void*)g,
        (__attribute__((address_space(3))) void*)l, 4, 0, 0);
}

// ---- pre-pass: x fp32 -> bf16 (RNE) into workspace.
__global__ void xcvt(const float* __restrict__ x, unsigned short* __restrict__ xb, int n4) {
    int i = blockIdx.x * blockDim.x + threadIdx.x;
    if (i < n4) {
        float4 v = ((const float4*)x)[i];
        ushort4 o;
        o.x = f2bf(v.x); o.y = f2bf(v.y); o.z = f2bf(v.z); o.w = f2bf(v.w);
        ((ushort4*)xb)[i] = o;
    }
}

__global__ __launch_bounds__(TPB, 4) void gnn(
    const unsigned short* __restrict__ xb,   // [N,24] bf16 gather table (in d_ws)
    const int*            __restrict__ ei,   // [2,E]; row 0 = src
    const float*          __restrict__ kv,   // [2,E]
    const float*          __restrict__ W,    // [64,48]
    float*                __restrict__ out)  // [N,64]
{
    __shared__ int            ei_s[NPB * DEG];       // 4 KB: src*48 byte offsets
    __shared__ unsigned short kv_s[2 * NPB * DEG];   // 4 KB bf16 kvals
    __shared__ unsigned short xv_s[NPB * DD];        // 1.5 KB own-node x (bf16)
    __shared__ unsigned short pre_s[NPB * PST];      // 3.5 KB bf16 pre rows
    __shared__ __align__(16) char tiles[4][2][2048]; // 16 KB per-wave dbuf gather tiles
                                                     // tile row: edge k at k*64B, 12 dwords used

    const int t    = threadIdx.x;
    const int lane = t & 63;
    const int w    = t >> 6;
    const int m    = lane & 31;      // A-row / B-col / C-col
    const int kh   = lane >> 5;      // K-half
    const int kh8  = kh * 8;
    const int t4   = lane >> 4;      // edge sub-slot 0..3 (DMA)
    const int dsl  = lane & 15;      // dimslot 0..15 (DMA; 12..15 land in pad)
    const int base = blockIdx.x * NPB;
    const char* xbc = (const char*)xb;

    // ---- cooperative staging: ei row0 (pre-scaled *48) + kv rows (bf16) + own x rows
    {
        const size_t eb = (size_t)base * DEG;        // 1024 edges per block
        int4 ev = ((const int4*)(ei + eb))[t];
        ev.x *= 48; ev.y *= 48; ev.z *= 48; ev.w *= 48;
        ((int4*)ei_s)[t] = ev;
        const float4 c0 = ((const float4*)(kv + eb))[t];
        const float4 c1 = ((const float4*)(kv + EE + eb))[t];
        ushort4 u0, u1;
        u0.x = f2bf(c0.x); u0.y = f2bf(c0.y); u0.z = f2bf(c0.z); u0.w = f2bf(c0.w);
        u1.x = f2bf(c1.x); u1.y = f2bf(c1.y); u1.z = f2bf(c1.z); u1.w = f2bf(c1.w);
        ((ushort4*)kv_s)[t] = u0;
        ((ushort4*)(kv_s + NPB * DEG))[t] = u1;
        if (t < (NPB * DD) / 4)                      // 192 ushort4 = 1536 B
            ((ushort4*)xv_s)[t] = ((const ushort4*)(xb + (size_t)base * DD))[t];
    }
    __syncthreads();

    // ================= Phase 1: DMA-pipelined aggregation =================
    const unsigned short* kvrow = kv_s + (m & 1) * (NPB * DEG);  // m=0->k0, m=1->k1
    const int n0 = w * NPW;

    // issue node nl's 8 DMA gathers into tiles[w][nl&1]
    #define ISSUE(nl) do {                                                     \
        char* tb_ = tiles[w][(nl) & 1];                                        \
        _Pragma("unroll")                                                      \
        for (int i_ = 0; i_ < 8; ++i_) {                                       \
            const int eo_ = ei_s[(nl) * DEG + i_ * 4 + t4];                    \
            const char* gp_ = (dsl < 12) ? (xbc + (unsigned)(eo_ + dsl * 4))   \
                                         : xbc;                                \
            gl_lds4(gp_, tb_ + i_ * 256);                                      \
        }                                                                      \
    } while (0)

    ISSUE(n0);

    #pragma unroll
    for (int p = 0; p < NPW; ++p) {
        const int nl = n0 + p;
        if (p < NPW - 1) {
            ISSUE(nl + 1);                           // 8 new DMAs in flight
            __builtin_amdgcn_s_waitcnt(0xF78);       // vmcnt(8): node nl's 8 done
        } else {
            __builtin_amdgcn_s_waitcnt(0xF70);       // vmcnt(0): drain
        }

        const unsigned short* tile = (const unsigned short*)tiles[w][p & 1];

        // B fragments: element (k, dim m) at tile[k*32 + m] (64B row stride)
        unsigned r0 = tile[(kh8 + 0) * 32 + m], r1 = tile[(kh8 + 1) * 32 + m];
        unsigned r2 = tile[(kh8 + 2) * 32 + m], r3 = tile[(kh8 + 3) * 32 + m];
        unsigned r4 = tile[(kh8 + 4) * 32 + m], r5 = tile[(kh8 + 5) * 32 + m];
        unsigned r6 = tile[(kh8 + 6) * 32 + m], r7 = tile[(kh8 + 7) * 32 + m];
        const short8 bf0 = mk8(pk(r0, r1), pk(r2, r3), pk(r4, r5), pk(r6, r7));
        unsigned s0 = tile[(16 + kh8 + 0) * 32 + m], s1 = tile[(16 + kh8 + 1) * 32 + m];
        unsigned s2 = tile[(16 + kh8 + 2) * 32 + m], s3 = tile[(16 + kh8 + 3) * 32 + m];
        unsigned s4 = tile[(16 + kh8 + 4) * 32 + m], s5 = tile[(16 + kh8 + 5) * 32 + m];
        unsigned s6 = tile[(16 + kh8 + 6) * 32 + m], s7 = tile[(16 + kh8 + 7) * 32 + m];
        const short8 bf1 = mk8(pk(s0, s1), pk(s2, s3), pk(s4, s5), pk(s6, s7));

        // A fragments from kv_s (same mapping as R7, which passed)
        const int el = nl * DEG + kh8;
        const short8 raw0 = *(const short8*)(kvrow + el);
        const short8 raw1 = *(const short8*)(kvrow + el + 16);
        const unsigned fill = (m == 2) ? 0x3F803F80u : 0u;   // ones row / zeros
        const short8 af0 = (m < 2) ? raw0 : mk8(fill, fill, fill, fill);
        const short8 af1 = (m < 2) ? raw1 : mk8(fill, fill, fill, fill);

        float16 acc;
        #pragma unroll
        for (int r = 0; r < 16; ++r) acc[r] = 0.f;
        acc = __builtin_amdgcn_mfma_f32_32x32x16_bf16(af0, bf0, acc, 0, 0, 0);
        acc = __builtin_amdgcn_mfma_f32_32x32x16_bf16(af1, bf1, acc, 0, 0, 0);

        // rows 0(a0),1(a1),2(sum) live in regs 0,1,2 of kh==0 lanes
        if (kh == 0 && m < DD) {
            const float sm = acc[2] * (1.f / 32.f);
            const float pv = bf2f((unsigned)xv_s[nl * DD + m]) - sm;
            pre_s[nl * PST + m]      = f2bf(acc[0] + pv);
            pre_s[nl * PST + 24 + m] = f2bf(acc[1] + pv);
        }
    }
    #undef ISSUE
    __syncthreads();

    // ================= Phase 2: out(32x64) = pre(32x48) @ W^T, waves 0,1 =================
    if (w < 2) {
        const int h = w * 32 + m;

        float16 acc;
        #pragma unroll
        for (int r = 0; r < 16; ++r) acc[r] = 0.f;

        #pragma unroll
        for (int kc = 0; kc < 3; ++kc) {
            const int c0 = kc * 16 + kh8;
            const short8 af = *(const short8*)(pre_s + m * PST + c0);
            const float* wr = W + h * 48 + c0;
            const float4 wA = ((const float4*)wr)[0];
            const float4 wB = ((const float4*)wr)[1];
            const short8 bf = mk8(pk(f2bf(wA.x), f2bf(wA.y)), pk(f2bf(wA.z), f2bf(wA.w)),
                                  pk(f2bf(wB.x), f2bf(wB.y)), pk(f2bf(wB.z), f2bf(wB.w)));
            acc = __builtin_amdgcn_mfma_f32_32x32x16_bf16(af, bf, acc, 0, 0, 0);
        }

        #pragma unroll
        for (int r = 0; r < 16; ++r) {
            const int row = (r & 3) + 8 * (r >> 2) + 4 * kh;   // node within block
            out[(size_t)(base + row) * HH + h] = acc[r];
        }
    }
}

extern "C" void kernel_launch(void* const* d_in, const int* in_sizes, int n_in,
                              void* d_out, int out_size, void* d_ws, size_t ws_size,
                              hipStream_t stream) {
    const float* x  = (const float*)d_in[0];
    const int*   ei = (const int*)d_in[1];
    const float* kv = (const float*)d_in[2];
    const float* W  = (const float*)d_in[3];
    float* out = (float*)d_out;

    unsigned short* xb = (unsigned short*)d_ws;            // 4.8 MB scratch
    const int n4 = NN * DD / 4;                            // 600000
    xcvt<<<(n4 + 255) / 256, 256, 0, stream>>>(x, xb, n4);

    const int grid = NN / NPB;                             // 3125, exact
    gnn<<<grid, TPB, 0, stream>>>(xb, ei, kv, W, out);
}

// Round 10
// 127.584 us; speedup vs baseline: 1.0200x; 1.0200x over previous
//
#include <hip/hip_runtime.h>

// net_86698209837440: N=100000, DEG=32 (edges sorted by tgt, deg==32), D=24, NK=2, H=64.
// R10: chunked async gathers. R7(1024 req/node, no pipe) == R9(512 req/node, DMA pipe)
// == 43us => binder is per-CU divergent-request throughput (~2-4 lanes/cyc), not
// latency, not instruction count. Fix: gather in 16B chunks - edge row (48B) = 3
// chunks, one 64-lane global_load_lds(16) covers 21.3 edges. 192 lane-requests per
// node-pair vs 1024. Depth-2 pipeline over pairs, vmcnt(3)/vmcnt(0).
// Phase 1: [k0;k1;ones](3x32) @ gathered-x(32x24) via 2x mfma_f32_32x32x16_bf16.
// Phase 2: pre(32x48 bf16, LDS) @ W^T via MFMA. fp32 accumulation.

#define NN   100000
#define DEG  32
#define EE   (NN * DEG)
#define DD   24
#define HH   64
#define NPB  32            // nodes per block; 100000 = 3125 * 32 exact
#define TPB  256
#define NPW  8             // nodes per wave (4 pairs)
#define PST  56            // pre_s row stride (ushorts)

typedef __attribute__((ext_vector_type(8)))  short short8;
typedef __attribute__((ext_vector_type(16))) float float16;

__device__ __forceinline__ unsigned short f2bf(float f) {
    union { float f; unsigned u; } v; v.f = f;
    unsigned r = v.u + 0x7fffu + ((v.u >> 16) & 1u);   // RNE
    return (unsigned short)(r >> 16);
}

__device__ __forceinline__ float bf2f(unsigned u) {
    union { unsigned i; float f; } v; v.i = u << 16; return v.f;
}

// lo16(a) -> low half, lo16(b) -> high half, one v_perm_b32
__device__ __forceinline__ unsigned pk(unsigned a, unsigned b) {
    return __builtin_amdgcn_perm(b, a, 0x05040100u);
}

__device__ __forceinline__ short8 mk8(unsigned u0, unsigned u1, unsigned u2, unsigned u3) {
    union { unsigned u[4]; short8 s; } p;
    p.u[0] = u0; p.u[1] = u1; p.u[2] = u2; p.u[3] = u3;
    return p.s;
}

// async 16B gather: per-lane global addr -> (wave-uniform LDS base + lane*16)
__device__ __forceinline__ void gl_lds16(const void* g, void* l) {
    __builtin_amdgcn_global_load_lds(
        (const __attribute__((address_space(1))) void*)g,
        (__attribute__((address_space(3))) void*)l, 16, 0, 0);
}

// ---- pre-pass: x fp32 -> bf16 (RNE) into workspace.
__global__ void xcvt(const float* __restrict__ x, unsigned short* __restrict__ xb, int n4) {
    int i = blockIdx.x * blockDim.x + threadIdx.x;
    if (i < n4) {
        float4 v = ((const float4*)x)[i];
        ushort4 o;
        o.x = f2bf(v.x); o.y = f2bf(v.y); o.z = f2bf(v.z); o.w = f2bf(v.w);
        ((ushort4*)xb)[i] = o;
    }
}

__global__ __launch_bounds__(TPB, 4) void gnn(
    const unsigned short* __restrict__ xb,   // [N,24] bf16 gather table (in d_ws)
    const int*            __restrict__ ei,   // [2,E]; row 0 = src
    const float*          __restrict__ kv,   // [2,E]
    const float*          __restrict__ W,    // [64,48]
    float*                __restrict__ out)  // [N,64]
{
    __shared__ int            ei_s[NPB * DEG];       // 4 KB: src*48 byte offsets
    __shared__ unsigned short kv_s[2 * NPB * DEG];   // 4 KB bf16 kvals
    __shared__ unsigned short xv_s[NPB * DD];        // 1.5 KB own-node x (bf16)
    __shared__ unsigned short pre_s[NPB * PST];      // 3.5 KB bf16 pre rows
    __shared__ __align__(16) char tiles[4][2][3072]; // 24 KB: per-wave dbuf pair-tiles
                                                     // 64 edges x 48B, edge-contiguous

    const int t    = threadIdx.x;
    const int lane = t & 63;
    const int w    = t >> 6;
    const int m    = lane & 31;      // A-row / B-col / C-col
    const int kh   = lane >> 5;      // K-half
    const int kh8  = kh * 8;
    const int base = blockIdx.x * NPB;
    const char* xbc = (const char*)xb;

    // ---- cooperative staging: ei row0 (pre-scaled *48) + kv rows (bf16) + own x rows
    {
        const size_t eb = (size_t)base * DEG;        // 1024 edges per block
        int4 ev = ((const int4*)(ei + eb))[t];
        ev.x *= 48; ev.y *= 48; ev.z *= 48; ev.w *= 48;
        ((int4*)ei_s)[t] = ev;
        const float4 c0 = ((const float4*)(kv + eb))[t];
        const float4 c1 = ((const float4*)(kv + EE + eb))[t];
        ushort4 u0, u1;
        u0.x = f2bf(c0.x); u0.y = f2bf(c0.y); u0.z = f2bf(c0.z); u0.w = f2bf(c0.w);
        u1.x = f2bf(c1.x); u1.y = f2bf(c1.y); u1.z = f2bf(c1.z); u1.w = f2bf(c1.w);
        ((ushort4*)kv_s)[t] = u0;
        ((ushort4*)(kv_s + NPB * DEG))[t] = u1;
        if (t < (NPB * DD) / 4)                      // 192 ushort4 = 1536 B
            ((ushort4*)xv_s)[t] = ((const ushort4*)(xb + (size_t)base * DD))[t];
    }
    __syncthreads();

    // ---- per-lane chunk constants: chunk ci = i*64 + lane covers edge ci/3, 16B piece ci%3
    int e_[3], co_[3];
    #pragma unroll
    for (int i = 0; i < 3; ++i) {
        const int ci = i * 64 + lane;
        e_[i]  = ci / 3;           // edge within pair (0..63)
        co_[i] = (ci % 3) * 16;    // byte offset within 48B row
    }

    // ================= Phase 1: pair-chunked DMA pipeline =================
    const unsigned short* kvrow = kv_s + (m & 1) * (NPB * DEG);  // m=0->k0, m=1->k1
    const int p0 = w * 4;                                        // first pair of this wave

    // issue pair pr's 3 chunk-DMAs (64 edges x 48B) into tiles[w][buf]
    #define ISSUE(pr, buf) do {                                                \
        char* tb_ = tiles[w][buf];                                             \
        _Pragma("unroll")                                                      \
        for (int i_ = 0; i_ < 3; ++i_) {                                       \
            const int off_ = ei_s[(pr) * 64 + e_[i_]];                         \
            gl_lds16(xbc + (unsigned)(off_ + co_[i_]), tb_ + i_ * 1024);       \
        }                                                                      \
    } while (0)

    // consume block-local node nl from tiles[w][buf]
    #define COMP(nl, buf) do {                                                 \
        const unsigned short* tile = (const unsigned short*)tiles[w][buf];     \
        const int lb = ((nl) & 1) * 32;                                        \
        unsigned r0 = tile[(lb + kh8 + 0) * 24 + m];                           \
        unsigned r1 = tile[(lb + kh8 + 1) * 24 + m];                           \
        unsigned r2 = tile[(lb + kh8 + 2) * 24 + m];                           \
        unsigned r3 = tile[(lb + kh8 + 3) * 24 + m];                           \
        unsigned r4 = tile[(lb + kh8 + 4) * 24 + m];                           \
        unsigned r5 = tile[(lb + kh8 + 5) * 24 + m];                           \
        unsigned r6 = tile[(lb + kh8 + 6) * 24 + m];                           \
        unsigned r7 = tile[(lb + kh8 + 7) * 24 + m];                           \
        const short8 bf0 = mk8(pk(r0, r1), pk(r2, r3), pk(r4, r5), pk(r6, r7)); \
        unsigned s0 = tile[(lb + 16 + kh8 + 0) * 24 + m];                      \
        unsigned s1 = tile[(lb + 16 + kh8 + 1) * 24 + m];                      \
        unsigned s2 = tile[(lb + 16 + kh8 + 2) * 24 + m];                      \
        unsigned s3 = tile[(lb + 16 + kh8 + 3) * 24 + m];                      \
        unsigned s4 = tile[(lb + 16 + kh8 + 4) * 24 + m];                      \
        unsigned s5 = tile[(lb + 16 + kh8 + 5) * 24 + m];                      \
        unsigned s6 = tile[(lb + 16 + kh8 + 6) * 24 + m];                      \
        unsigned s7 = tile[(lb + 16 + kh8 + 7) * 24 + m];                      \
        const short8 bf1 = mk8(pk(s0, s1), pk(s2, s3), pk(s4, s5), pk(s6, s7)); \
        const int el = (nl) * DEG + kh8;                                       \
        const short8 raw0 = *(const short8*)(kvrow + el);                      \
        const short8 raw1 = *(const short8*)(kvrow + el + 16);                 \
        const unsigned fill = (m == 2) ? 0x3F803F80u : 0u;                     \
        const short8 af0 = (m < 2) ? raw0 : mk8(fill, fill, fill, fill);       \
        const short8 af1 = (m < 2) ? raw1 : mk8(fill, fill, fill, fill);       \
        float16 acc;                                                           \
        _Pragma("unroll")                                                      \
        for (int r = 0; r < 16; ++r) acc[r] = 0.f;                             \
        acc = __builtin_amdgcn_mfma_f32_32x32x16_bf16(af0, bf0, acc, 0, 0, 0); \
        acc = __builtin_amdgcn_mfma_f32_32x32x16_bf16(af1, bf1, acc, 0, 0, 0); \
        if (kh == 0 && m < DD) {                                               \
            const float sm = acc[2] * (1.f / 32.f);                            \
            const float pv = bf2f((unsigned)xv_s[(nl) * DD + m]) - sm;         \
            pre_s[(nl) * PST + m]      = f2bf(acc[0] + pv);                    \
            pre_s[(nl) * PST + 24 + m] = f2bf(acc[1] + pv);                    \
        }                                                                      \
    } while (0)

    ISSUE(p0, 0);

    #pragma unroll
    for (int p = 0; p < 4; ++p) {
        if (p < 3) {
            ISSUE(p0 + p + 1, (p + 1) & 1);          // next pair's 3 DMAs in flight
            __builtin_amdgcn_s_waitcnt(0xF73);       // vmcnt(3): pair p's 3 done
        } else {
            __builtin_amdgcn_s_waitcnt(0xF70);       // vmcnt(0): drain
        }
        COMP(p0 * 2 + 2 * p,     p & 1);
        COMP(p0 * 2 + 2 * p + 1, p & 1);
    }
    #undef ISSUE
    #undef COMP
    __syncthreads();

    // ================= Phase 2: out(32x64) = pre(32x48) @ W^T, waves 0,1 =================
    if (w < 2) {
        const int h = w * 32 + m;

        float16 acc;
        #pragma unroll
        for (int r = 0; r < 16; ++r) acc[r] = 0.f;

        #pragma unroll
        for (int kc = 0; kc < 3; ++kc) {
            const int c0 = kc * 16 + kh8;
            const short8 af = *(const short8*)(pre_s + m * PST + c0);
            const float* wr = W + h * 48 + c0;
            const float4 wA = ((const float4*)wr)[0];
            const float4 wB = ((const float4*)wr)[1];
            const short8 bf = mk8(pk(f2bf(wA.x), f2bf(wA.y)), pk(f2bf(wA.z), f2bf(wA.w)),
                                  pk(f2bf(wB.x), f2bf(wB.y)), pk(f2bf(wB.z), f2bf(wB.w)));
            acc = __builtin_amdgcn_mfma_f32_32x32x16_bf16(af, bf, acc, 0, 0, 0);
        }

        #pragma unroll
        for (int r = 0; r < 16; ++r) {
            const int row = (r & 3) + 8 * (r >> 2) + 4 * kh;   // node within block
            out[(size_t)(base + row) * HH + h] = acc[r];
        }
    }
}

extern "C" void kernel_launch(void* const* d_in, const int* in_sizes, int n_in,
                              void* d_out, int out_size, void* d_ws, size_t ws_size,
                              hipStream_t stream) {
    const float* x  = (const float*)d_in[0];
    const int*   ei = (const int*)d_in[1];
    const float* kv = (const float*)d_in[2];
    const float* W  = (const float*)d_in[3];
    float* out = (float*)d_out;

    unsigned short* xb = (unsigned short*)d_ws;            // 4.8 MB scratch
    const int n4 = NN * DD / 4;                            // 600000
    xcvt<<<(n4 + 255) / 256, 256, 0, stream>>>(x, xb, n4);

    const int grid = NN / NPB;                             // 3125, exact
    gnn<<<grid, TPB, 0, stream>>>(xb, ei, kv, W, out);
}